// Round 1
// baseline (11066.918 us; speedup 1.0000x reference)
//
#include <hip/hip_runtime.h>

#define R 5
#define U 100000
#define M 50000
#define E 2000000
#define F 10
#define D 50

// workspace layout (floats):
//   sum_i : R*M*F   (per-relation item neighbor sums, fwd direction)
//   cnt_i : R*M
//   sum_u : R*U*F   (per-relation user neighbor sums, rev direction)
//   cnt_u : R*U
#define SUM_I_OFF 0
#define CNT_I_OFF ((size_t)R * M * F)                    // 2,500,000
#define SUM_U_OFF (CNT_I_OFF + (size_t)R * M)            // 2,750,000
#define CNT_U_OFF (SUM_U_OFF + (size_t)R * U * F)        // 7,750,000
#define WS_FLOATS (CNT_U_OFF + (size_t)R * U)            // 8,250,000

// One thread per edge (grid-stride over R*E). Gathers F floats from each
// side's feature table (tables are 2-4 MB/relation -> L2/LLC resident) and
// scatters with f32 atomics into the per-node accumulators.
__global__ void scatter_edges(const int* __restrict__ esrc,
                              const int* __restrict__ edst,
                              const float* __restrict__ feat_u_fwd,
                              const float* __restrict__ feat_i_rev,
                              float* __restrict__ ws) {
    float* sum_i = ws + SUM_I_OFF;
    float* cnt_i = ws + CNT_I_OFF;
    float* sum_u = ws + SUM_U_OFF;
    float* cnt_u = ws + CNT_U_OFF;

    const int total = R * E;  // 10,000,000
    for (int idx = blockIdx.x * blockDim.x + threadIdx.x; idx < total;
         idx += gridDim.x * blockDim.x) {
        int r = idx / E;
        int s = esrc[idx];  // user endpoint
        int d = edst[idx];  // item endpoint

        const float* fu = feat_u_fwd + ((size_t)r * U + s) * F;  // src feats (fwd)
        const float* fi = feat_i_rev + ((size_t)r * M + d) * F;  // src feats (rev)
        float* si = sum_i + ((size_t)r * M + d) * F;             // item accumulator
        float* su = sum_u + ((size_t)r * U + s) * F;             // user accumulator

#pragma unroll
        for (int f = 0; f < F; ++f) {
            atomicAdd(si + f, fu[f]);
            atomicAdd(su + f, fi[f]);
        }
        atomicAdd(cnt_i + (size_t)r * M + d, 1.0f);
        atomicAdd(cnt_u + (size_t)r * U + s, 1.0f);
    }
}

// One thread per output element (n, r, d). out[n*R*D + r*D + d] =
//   fc_self(feat_dst) + fc_neigh(sum/cnt) + b
__global__ void finalize_nodes(int N,                      // number of dst nodes
                               const float* __restrict__ feat_dst,  // (R, N, F)
                               const float* __restrict__ w_self,    // (R, F, D)
                               const float* __restrict__ w_neigh,   // (R, F, D)
                               const float* __restrict__ bias,      // (R, D)
                               const float* __restrict__ sum,       // (R, N, F)
                               const float* __restrict__ cnt,       // (R, N)
                               float* __restrict__ out) {           // (N, R*D)
    int idx = blockIdx.x * blockDim.x + threadIdx.x;
    int total = N * R * D;
    if (idx >= total) return;
    int n = idx / (R * D);
    int rd = idx - n * (R * D);
    int r = rd / D;
    int d = rd - r * D;

    const float* fd = feat_dst + ((size_t)r * N + n) * F;
    const float* sn = sum + ((size_t)r * N + n) * F;
    float c = cnt[(size_t)r * N + n];
    float inv = 1.0f / fmaxf(c, 1.0f);

    const float* wsp = w_self + (size_t)r * F * D + d;
    const float* wnp = w_neigh + (size_t)r * F * D + d;

    float acc_self = bias[r * D + d];
    float acc_n = 0.0f;
#pragma unroll
    for (int f = 0; f < F; ++f) {
        acc_self += fd[f] * wsp[(size_t)f * D];
        acc_n += sn[f] * wnp[(size_t)f * D];
    }
    out[idx] = acc_self + acc_n * inv;
}

extern "C" void kernel_launch(void* const* d_in, const int* in_sizes, int n_in,
                              void* d_out, int out_size, void* d_ws, size_t ws_size,
                              hipStream_t stream) {
    const int* edges_src = (const int*)d_in[0];
    const int* edges_dst = (const int*)d_in[1];
    const float* feat_u_fwd = (const float*)d_in[2];
    const float* feat_i_fwd = (const float*)d_in[3];
    const float* feat_i_rev = (const float*)d_in[4];
    const float* feat_u_rev = (const float*)d_in[5];
    const float* w_self_fwd = (const float*)d_in[6];
    const float* w_neigh_fwd = (const float*)d_in[7];
    const float* b_fwd = (const float*)d_in[8];
    const float* w_self_rev = (const float*)d_in[9];
    const float* w_neigh_rev = (const float*)d_in[10];
    const float* b_rev = (const float*)d_in[11];

    float* out = (float*)d_out;
    float* out_u = out;                          // (U, R*D) first
    float* out_i = out + (size_t)U * R * D;      // (M, R*D) second
    float* ws = (float*)d_ws;

    // zero the accumulators every call (harness does not re-poison between replays)
    hipMemsetAsync(d_ws, 0, WS_FLOATS * sizeof(float), stream);

    // edge scatter
    {
        int blocks = 4096;
        scatter_edges<<<blocks, 256, 0, stream>>>(edges_src, edges_dst,
                                                  feat_u_fwd, feat_i_rev, ws);
    }

    // finalize users: (R,U) accumulators + feat_u_rev + rev weights -> out_u
    {
        int total = U * R * D;  // 25,000,000
        int blocks = (total + 255) / 256;
        finalize_nodes<<<blocks, 256, 0, stream>>>(U, feat_u_rev, w_self_rev,
                                                   w_neigh_rev, b_rev,
                                                   ws + SUM_U_OFF, ws + CNT_U_OFF,
                                                   out_u);
    }
    // finalize items
    {
        int total = M * R * D;  // 12,500,000
        int blocks = (total + 255) / 256;
        finalize_nodes<<<blocks, 256, 0, stream>>>(M, feat_i_fwd, w_self_fwd,
                                                   w_neigh_fwd, b_fwd,
                                                   ws + SUM_I_OFF, ws + CNT_I_OFF,
                                                   out_i);
    }
}

// Round 3
// 1484.648 us; speedup vs baseline: 7.4542x; 7.4542x over previous
//
#include <hip/hip_runtime.h>

#define R 5
#define U 100000
#define M 50000
#define E 2000000
#define F 10
#define D 50

#define TE (R * E)                      // 10,000,000 edges per direction
#define NBLK 256                        // phase A/C block count
#define CHUNK ((TE + NBLK - 1) / NBLK)  // 39,063 edges per block
#define BSZ 256

#define KS_U (R * U)                    // 500,000 user keys
#define KS_I (R * M)                    // 250,000 item keys
#define NBU_U ((KS_U + 255) / 256)      // 1954 user buckets
#define NBU_I ((KS_I + 255) / 256)      // 977 item buckets
#define NBU_T (NBU_U + NBU_I)           // 2931
#define OFFI (NBU_U * NBLK)             // 500,224 (item region start in ghist/S)
#define GTOT (OFFI + NBU_I * NBLK)      // 750,336
#define NS1 ((GTOT + 1023) / 1024)      // 733 scan blocks

// ======================= bucketed counting-sort path =======================

// Per-block LDS histogram over both directions' buckets. No global atomics.
__global__ __launch_bounds__(BSZ) void phaseA(const int* __restrict__ esrc,
                                              const int* __restrict__ edst,
                                              unsigned* __restrict__ ghist) {
    __shared__ unsigned hist[NBU_T];
    for (int i = threadIdx.x; i < NBU_T; i += BSZ) hist[i] = 0;
    __syncthreads();
    int b = blockIdx.x;
    int lo = b * CHUNK, hi = min(lo + CHUNK, TE);
    for (int i = lo + threadIdx.x; i < hi; i += BSZ) {
        unsigned r = (unsigned)i / (unsigned)E;
        int s = esrc[i], d = edst[i];
        unsigned ku = r * U + (unsigned)s;
        unsigned ki = r * M + (unsigned)d;
        atomicAdd(&hist[ku >> 8], 1u);
        atomicAdd(&hist[NBU_U + (ki >> 8)], 1u);
    }
    __syncthreads();
    for (int j = threadIdx.x; j < NBU_T; j += BSZ) {
        unsigned idx = (j < NBU_U) ? (unsigned)j * NBLK + b
                                   : OFFI + (unsigned)(j - NBU_U) * NBLK + b;
        ghist[idx] = hist[j];
    }
}

// Exclusive scan, 3 kernels. scan1: per-1024-chunk scan + chunk totals.
__global__ __launch_bounds__(BSZ) void scan1(const unsigned* __restrict__ g,
                                             unsigned* __restrict__ S,
                                             unsigned* __restrict__ psum) {
    __shared__ unsigned sh[BSZ];
    int base = blockIdx.x * 1024 + threadIdx.x * 4;
    unsigned v[4], tsum = 0;
    for (int k = 0; k < 4; k++) {
        int i = base + k;
        v[k] = (i < GTOT) ? g[i] : 0u;
        tsum += v[k];
    }
    sh[threadIdx.x] = tsum;
    __syncthreads();
    for (int off = 1; off < BSZ; off <<= 1) {
        unsigned t = (threadIdx.x >= off) ? sh[threadIdx.x - off] : 0u;
        __syncthreads();
        sh[threadIdx.x] += t;
        __syncthreads();
    }
    unsigned ex = sh[threadIdx.x] - tsum;
    for (int k = 0; k < 4; k++) {
        int i = base + k;
        if (i < GTOT) S[i] = ex;
        ex += v[k];
    }
    if (threadIdx.x == BSZ - 1) psum[blockIdx.x] = sh[BSZ - 1];
}

__global__ __launch_bounds__(BSZ) void scan2(unsigned* __restrict__ psum) {
    __shared__ unsigned sh[BSZ];
    unsigned v[3], tsum = 0;
    int base = threadIdx.x * 3;
    for (int k = 0; k < 3; k++) {
        int i = base + k;
        v[k] = (i < NS1) ? psum[i] : 0u;
        tsum += v[k];
    }
    sh[threadIdx.x] = tsum;
    __syncthreads();
    for (int off = 1; off < BSZ; off <<= 1) {
        unsigned t = (threadIdx.x >= off) ? sh[threadIdx.x - off] : 0u;
        __syncthreads();
        sh[threadIdx.x] += t;
        __syncthreads();
    }
    unsigned ex = sh[threadIdx.x] - tsum;
    for (int k = 0; k < 3; k++) {
        int i = base + k;
        if (i < NS1) psum[i] = ex;
        ex += v[k];
    }
}

__global__ __launch_bounds__(BSZ) void scan3(unsigned* __restrict__ S,
                                             const unsigned* __restrict__ psum) {
    unsigned add = psum[blockIdx.x];
    int base = blockIdx.x * 1024 + threadIdx.x * 4;
    for (int k = 0; k < 4; k++) {
        int i = base + k;
        if (i < GTOT) S[i] += add;
    }
}

// Scatter edges into bucket-grouped payload array. LDS cursor atomics only.
// payload = local_node(8b) | src_id(<<8): src<100K fits 17 bits -> 25 bits.
__global__ __launch_bounds__(BSZ) void phaseC(const int* __restrict__ esrc,
                                              const int* __restrict__ edst,
                                              const unsigned* __restrict__ S,
                                              unsigned* __restrict__ sorted) {
    __shared__ unsigned cur[NBU_T];
    int b = blockIdx.x;
    for (int j = threadIdx.x; j < NBU_T; j += BSZ) {
        unsigned idx = (j < NBU_U) ? (unsigned)j * NBLK + b
                                   : OFFI + (unsigned)(j - NBU_U) * NBLK + b;
        cur[j] = S[idx];
    }
    __syncthreads();
    int lo = b * CHUNK, hi = min(lo + CHUNK, TE);
    for (int i = lo + threadIdx.x; i < hi; i += BSZ) {
        unsigned r = (unsigned)i / (unsigned)E;
        int s = esrc[i], d = edst[i];
        unsigned ku = r * U + (unsigned)s;
        unsigned ki = r * M + (unsigned)d;
        unsigned pu = atomicAdd(&cur[ku >> 8], 1u);
        sorted[pu] = (ku & 255u) | ((unsigned)d << 8);   // user list: src=item id
        unsigned pi = atomicAdd(&cur[NBU_U + (ki >> 8)], 1u);
        sorted[pi] = (ki & 255u) | ((unsigned)s << 8);   // item list: src=user id
    }
}

// One block per bucket: LDS-accumulate neighbor sums, then fused projection.
__global__ __launch_bounds__(BSZ) void phaseD(
    const unsigned* __restrict__ sorted, const unsigned* __restrict__ S,
    const float* __restrict__ fsrc_u, const float* __restrict__ fdst_u,
    const float* __restrict__ wsf_u, const float* __restrict__ wnf_u,
    const float* __restrict__ bia_u,
    const float* __restrict__ fsrc_i, const float* __restrict__ fdst_i,
    const float* __restrict__ wsf_i, const float* __restrict__ wnf_i,
    const float* __restrict__ bia_i,
    float* __restrict__ out_u, float* __restrict__ out_i) {
    __shared__ float acc[256 * F];
    __shared__ float cnt[256];
    bool isU = blockIdx.x < NBU_U;
    int j = isU ? blockIdx.x : blockIdx.x - NBU_U;
    unsigned N = isU ? U : M;
    unsigned NSRC = isU ? M : U;  // src feature table rows per relation
    const float* fsrc = isU ? fsrc_u : fsrc_i;

    unsigned sbase = isU ? 0u : (unsigned)OFFI;
    unsigned lo = S[sbase + (unsigned)j * NBLK];
    unsigned hi = (!isU && j + 1 == NBU_I) ? (unsigned)(2 * TE)
                                           : S[sbase + (unsigned)(j + 1) * NBLK];

    for (int t = threadIdx.x; t < 256 * F; t += BSZ) acc[t] = 0.f;
    for (int t = threadIdx.x; t < 256; t += BSZ) cnt[t] = 0.f;
    __syncthreads();

    unsigned keybase = (unsigned)j * 256u;
    for (unsigned e = lo + threadIdx.x; e < hi; e += BSZ) {
        unsigned pay = sorted[e];
        unsigned local = pay & 255u;
        unsigned src = pay >> 8;
        unsigned r = (keybase + local) / N;
        const float2* row = (const float2*)(fsrc + ((size_t)r * NSRC + src) * F);
        float* a = acc + local * F;
#pragma unroll
        for (int k = 0; k < 5; k++) {
            float2 v = row[k];
            atomicAdd(a + 2 * k, v.x);
            atomicAdd(a + 2 * k + 1, v.y);
        }
        atomicAdd(&cnt[local], 1.f);
    }
    __syncthreads();

    const float* fdst = isU ? fdst_u : fdst_i;
    const float* wsf = isU ? wsf_u : wsf_i;
    const float* wnf = isU ? wnf_u : wnf_i;
    const float* bia = isU ? bia_u : bia_i;
    float* out = isU ? out_u : out_i;

    for (int o = threadIdx.x; o < 256 * D; o += BSZ) {
        int local = o / D, d = o - local * D;
        unsigned key = keybase + (unsigned)local;
        if (key >= (unsigned)(R)*N) continue;  // tail bucket beyond keyspace
        unsigned r = key / N, n = key - r * N;
        float inv = 1.f / fmaxf(cnt[local], 1.f);
        const float* fd = fdst + ((size_t)r * N + n) * F;
        const float* a = acc + local * F;
        const float* wsp = wsf + (size_t)r * F * D + d;
        const float* wnp = wnf + (size_t)r * F * D + d;
        float o1 = bia[r * D + d], o2 = 0.f;
#pragma unroll
        for (int f = 0; f < F; f++) {
            o1 += fd[f] * wsp[(size_t)f * D];
            o2 += a[f] * wnp[(size_t)f * D];
        }
        out[(size_t)n * (R * D) + r * D + d] = o1 + o2 * inv;
    }
}

// ======================= round-1 fallback (small ws) =======================
#define SUM_I_OFF 0
#define CNT_I_OFF ((size_t)R * M * F)
#define SUM_U_OFF (CNT_I_OFF + (size_t)R * M)
#define CNT_U_OFF (SUM_U_OFF + (size_t)R * U * F)
#define WS_FLOATS (CNT_U_OFF + (size_t)R * U)

__global__ void scatter_edges(const int* __restrict__ esrc, const int* __restrict__ edst,
                              const float* __restrict__ feat_u_fwd,
                              const float* __restrict__ feat_i_rev, float* __restrict__ ws) {
    float* sum_i = ws + SUM_I_OFF;
    float* cnt_i = ws + CNT_I_OFF;
    float* sum_u = ws + SUM_U_OFF;
    float* cnt_u = ws + CNT_U_OFF;
    const int total = R * E;
    for (int idx = blockIdx.x * blockDim.x + threadIdx.x; idx < total;
         idx += gridDim.x * blockDim.x) {
        int r = idx / E;
        int s = esrc[idx], d = edst[idx];
        const float* fu = feat_u_fwd + ((size_t)r * U + s) * F;
        const float* fi = feat_i_rev + ((size_t)r * M + d) * F;
        float* si = sum_i + ((size_t)r * M + d) * F;
        float* su = sum_u + ((size_t)r * U + s) * F;
#pragma unroll
        for (int f = 0; f < F; ++f) {
            atomicAdd(si + f, fu[f]);
            atomicAdd(su + f, fi[f]);
        }
        atomicAdd(cnt_i + (size_t)r * M + d, 1.0f);
        atomicAdd(cnt_u + (size_t)r * U + s, 1.0f);
    }
}

__global__ void finalize_nodes(int N, const float* __restrict__ feat_dst,
                               const float* __restrict__ w_self, const float* __restrict__ w_neigh,
                               const float* __restrict__ bias, const float* __restrict__ sum,
                               const float* __restrict__ cnt, float* __restrict__ out) {
    int idx = blockIdx.x * blockDim.x + threadIdx.x;
    int total = N * R * D;
    if (idx >= total) return;
    int n = idx / (R * D);
    int rd = idx - n * (R * D);
    int r = rd / D;
    int d = rd - r * D;
    const float* fd = feat_dst + ((size_t)r * N + n) * F;
    const float* sn = sum + ((size_t)r * N + n) * F;
    float inv = 1.0f / fmaxf(cnt[(size_t)r * N + n], 1.0f);
    const float* wsp = w_self + (size_t)r * F * D + d;
    const float* wnp = w_neigh + (size_t)r * F * D + d;
    float acc_self = bias[r * D + d];
    float acc_n = 0.0f;
#pragma unroll
    for (int f = 0; f < F; ++f) {
        acc_self += fd[f] * wsp[(size_t)f * D];
        acc_n += sn[f] * wnp[(size_t)f * D];
    }
    out[idx] = acc_self + acc_n * inv;
}

// ======================= launch =======================
extern "C" void kernel_launch(void* const* d_in, const int* in_sizes, int n_in,
                              void* d_out, int out_size, void* d_ws, size_t ws_size,
                              hipStream_t stream) {
    const int* edges_src = (const int*)d_in[0];
    const int* edges_dst = (const int*)d_in[1];
    const float* feat_u_fwd = (const float*)d_in[2];
    const float* feat_i_fwd = (const float*)d_in[3];
    const float* feat_i_rev = (const float*)d_in[4];
    const float* feat_u_rev = (const float*)d_in[5];
    const float* w_self_fwd = (const float*)d_in[6];
    const float* w_neigh_fwd = (const float*)d_in[7];
    const float* b_fwd = (const float*)d_in[8];
    const float* w_self_rev = (const float*)d_in[9];
    const float* w_neigh_rev = (const float*)d_in[10];
    const float* b_rev = (const float*)d_in[11];

    float* out = (float*)d_out;
    float* out_u = out;
    float* out_i = out + (size_t)U * R * D;

    size_t need = ((size_t)2 * TE + 2ull * GTOT + 1024ull) * 4ull;  // ~86 MB
    if (ws_size >= need) {
        unsigned* sorted = (unsigned*)d_ws;            // 2*TE
        unsigned* ghist = sorted + (size_t)2 * TE;     // GTOT
        unsigned* S = ghist + GTOT;                    // GTOT
        unsigned* psum = S + GTOT;                     // 1024

        phaseA<<<NBLK, BSZ, 0, stream>>>(edges_src, edges_dst, ghist);
        scan1<<<NS1, BSZ, 0, stream>>>(ghist, S, psum);
        scan2<<<1, BSZ, 0, stream>>>(psum);
        scan3<<<NS1, BSZ, 0, stream>>>(S, psum);
        phaseC<<<NBLK, BSZ, 0, stream>>>(edges_src, edges_dst, S, sorted);
        phaseD<<<NBU_T, BSZ, 0, stream>>>(sorted, S,
                                          feat_i_rev, feat_u_rev, w_self_rev, w_neigh_rev, b_rev,
                                          feat_u_fwd, feat_i_fwd, w_self_fwd, w_neigh_fwd, b_fwd,
                                          out_u, out_i);
    } else {
        // fallback: round-1 global-atomic path
        float* ws = (float*)d_ws;
        hipMemsetAsync(d_ws, 0, WS_FLOATS * sizeof(float), stream);
        scatter_edges<<<4096, 256, 0, stream>>>(edges_src, edges_dst, feat_u_fwd, feat_i_rev, ws);
        finalize_nodes<<<(U * R * D + 255) / 256, 256, 0, stream>>>(
            U, feat_u_rev, w_self_rev, w_neigh_rev, b_rev, ws + SUM_U_OFF, ws + CNT_U_OFF, out_u);
        finalize_nodes<<<(M * R * D + 255) / 256, 256, 0, stream>>>(
            M, feat_i_fwd, w_self_fwd, w_neigh_fwd, b_fwd, ws + SUM_I_OFF, ws + CNT_I_OFF, out_i);
    }
}